// Round 8
// baseline (771.408 us; speedup 1.0000x reference)
//
#include <hip/hip_runtime.h>
#include <hip/hip_cooperative_groups.h>
#include <hip/hip_bf16.h>
#include <stdint.h>

namespace cg = cooperative_groups;

// BOXLoss: N=1e6 rows, G=32 groups -> scalar loss.
// FUSED cooperative kernel (1 dispatch): pack bits + per-block conf partials ->
// grid.sync -> conf reduce (redundant per block) + log-space mx partials ->
// grid.sync -> mx reduce + focal loss partials -> grid.sync -> block0 final.
// No global atomics; all reductions fixed-order (deterministic, graph-replay safe).
// Fallback: r7's 4-kernel path if cooperative launch is unavailable.

constexpr float kClamp = 1e-4f;
constexpr uint32_t kNegInfKey = 0x007FFFFFu;  // fkey(-inf), legacy path

__device__ inline uint32_t fkey(float f) {
    uint32_t u = __float_as_uint(f);
    return (u & 0x80000000u) ? ~u : (u | 0x80000000u);
}
__device__ inline float funkey(uint32_t k) {
    uint32_t u = (k & 0x80000000u) ? (k ^ 0x80000000u) : ~k;
    return __uint_as_float(u);
}

// ---------------------------- fused kernel ----------------------------
__global__ __launch_bounds__(256, 4)
void fused_kernel(const float* __restrict__ logits,
                  const float* __restrict__ scores,
                  const float* __restrict__ iouMap,
                  const int4*  __restrict__ boxes4,
                  const void*  __restrict__ denom_ptr,
                  float* __restrict__ out,
                  float* __restrict__ conf_part,   // [nb*32]
                  float* __restrict__ mx_part,     // [nb*32]
                  float* __restrict__ lsum,        // [nb]
                  uint32_t* __restrict__ bits,     // [n]
                  int n, long long nchunks) {
    cg::grid_group grid = cg::this_grid();
    __shared__ uint32_t conf_u[32];
    __shared__ float conf_s[32];
    __shared__ float invmx[32];
    __shared__ float smax_w[4][32];
    __shared__ float red[32][33];
    __shared__ float wsum[4];
    const int tid = threadIdx.x;
    const int bid = blockIdx.x;
    const int nb  = gridDim.x;
    const long long nthreads = (long long)nb * blockDim.x;

    // ---- Phase 1: pack bitmask + per-block conf maxima (8 lanes = 1 row) ----
    if (tid < 32) conf_u[tid] = 0u;
    __syncthreads();
    {
        const int g0 = (tid & 7) * 4;
        float r0 = 0.f, r1 = 0.f, r2 = 0.f, r3 = 0.f;
        for (long long c = (long long)bid * blockDim.x + tid; c < nchunks; c += nthreads) {
            int4 v = boxes4[c];
            uint32_t nib = (uint32_t)(v.x > 0) | ((uint32_t)(v.y > 0) << 1) |
                           ((uint32_t)(v.z > 0) << 2) | ((uint32_t)(v.w > 0) << 3);
            long long row = c >> 3;
            uint32_t r = nib << ((tid & 7) * 4);
            r |= __shfl_xor(r, 1);
            r |= __shfl_xor(r, 2);
            r |= __shfl_xor(r, 4);              // 8-lane OR -> full row mask
            if ((tid & 7) == 0) bits[row] = r;
            float s = scores[row];              // broadcast within 8 lanes, cached
            r0 = (nib & 1u) ? fmaxf(r0, s) : r0;
            r1 = (nib & 2u) ? fmaxf(r1, s) : r1;
            r2 = (nib & 4u) ? fmaxf(r2, s) : r2;
            r3 = (nib & 8u) ? fmaxf(r3, s) : r3;
        }
        for (int off = 8; off < 64; off <<= 1) {  // lanes sharing the column set
            r0 = fmaxf(r0, __shfl_xor(r0, off));
            r1 = fmaxf(r1, __shfl_xor(r1, off));
            r2 = fmaxf(r2, __shfl_xor(r2, off));
            r3 = fmaxf(r3, __shfl_xor(r3, off));
        }
        if ((tid & 63) < 8) {                   // one-time LDS merge (scores >= 0)
            atomicMax(&conf_u[g0 + 0], __float_as_uint(r0));
            atomicMax(&conf_u[g0 + 1], __float_as_uint(r1));
            atomicMax(&conf_u[g0 + 2], __float_as_uint(r2));
            atomicMax(&conf_u[g0 + 3], __float_as_uint(r3));
        }
        __syncthreads();
        if (tid < 32) conf_part[bid * 32 + tid] = __uint_as_float(conf_u[tid]);
    }
    __threadfence();
    grid.sync();

    // ---- Phase 2a: reduce conf over all blocks (each block redundantly) ----
    {
        const float4* cp4 = (const float4*)conf_part;
        float4 m = make_float4(0.f, 0.f, 0.f, 0.f);
        const int slot = tid & 7, slice = tid >> 3;
        for (int b = slice; b < nb; b += 32) {
            float4 v = cp4[b * 8 + slot];
            m.x = fmaxf(m.x, v.x); m.y = fmaxf(m.y, v.y);
            m.z = fmaxf(m.z, v.z); m.w = fmaxf(m.w, v.w);
        }
        red[slice][slot * 4 + 0] = m.x; red[slice][slot * 4 + 1] = m.y;
        red[slice][slot * 4 + 2] = m.z; red[slice][slot * 4 + 3] = m.w;
        __syncthreads();
        if (tid < 32) {
            float v = red[0][tid];
            for (int s = 1; s < 32; ++s) v = fmaxf(v, red[s][tid]);
            conf_s[tid] = v;
        }
        __syncthreads();
    }

    // ---- Phase 2b: mx partials. 4 threads/row, 8 columns each (no spill) ----
    {
        const int chunk = tid & 3;
        float cf[8], lmax[8];
#pragma unroll
        for (int k = 0; k < 8; ++k) { cf[k] = conf_s[chunk * 8 + k]; lmax[k] = -__builtin_inff(); }
        const int slots = (int)(nthreads >> 2);
        for (int row = (bid * blockDim.x + tid) >> 2; row < n; row += slots) {
            uint32_t mc = (bits[row] >> (chunk * 8)) & 0xFFu;
            if (!mc) continue;
            float l2s = log2f(scores[row]);     // -inf for s==0
            float l2i = log2f(iouMap[row]);
#pragma unroll
            for (int k = 0; k < 8; ++k) {
                float t0 = cf[k] * l2s;
                t0 = (t0 != t0) ? 0.0f : t0;    // 0*-inf (pow(0,0)=1) -> 0
                float t = t0 + l2i;
                lmax[k] = (mc & (1u << k)) ? fmaxf(lmax[k], t) : lmax[k];
            }
        }
#pragma unroll
        for (int off = 4; off < 64; off <<= 1) {
#pragma unroll
            for (int k = 0; k < 8; ++k) lmax[k] = fmaxf(lmax[k], __shfl_xor(lmax[k], off));
        }
        const int wave = tid >> 6, lane = tid & 63;
        if (lane < 4) {
#pragma unroll
            for (int k = 0; k < 8; ++k) smax_w[wave][lane * 8 + k] = lmax[k];
        }
        __syncthreads();
        if (tid < 32)
            mx_part[bid * 32 + tid] = fmaxf(fmaxf(smax_w[0][tid], smax_w[1][tid]),
                                            fmaxf(smax_w[2][tid], smax_w[3][tid]));
    }
    __threadfence();
    grid.sync();

    // ---- Phase 3a: reduce mx over blocks -> invmx ----
    {
        const float4* mp4 = (const float4*)mx_part;
        const float ninf = -__builtin_inff();
        float4 m = make_float4(ninf, ninf, ninf, ninf);
        const int slot = tid & 7, slice = tid >> 3;
        for (int b = slice; b < nb; b += 32) {
            float4 v = mp4[b * 8 + slot];
            m.x = fmaxf(m.x, v.x); m.y = fmaxf(m.y, v.y);
            m.z = fmaxf(m.z, v.z); m.w = fmaxf(m.w, v.w);
        }
        red[slice][slot * 4 + 0] = m.x; red[slice][slot * 4 + 1] = m.y;
        red[slice][slot * 4 + 2] = m.z; red[slice][slot * 4 + 3] = m.w;
        __syncthreads();
        if (tid < 32) {
            float v = red[0][tid];
            for (int s = 1; s < 32; ++s) v = fmaxf(v, red[s][tid]);
            invmx[tid] = 1.0f / (exp2f(v) + kClamp);  // exp2(-inf)=0 for unused cols
        }
        __syncthreads();
    }

    // ---- Phase 3b: focal loss partials ----
    {
        float acc = 0.0f;
        for (long long row = (long long)bid * blockDim.x + tid; row < n; row += nthreads) {
            uint32_t m = bits[row];
            float x = logits[row];
            float p = 1.0f / (1.0f + expf(-x));
            p = fminf(fmaxf(p, kClamp), 1.0f - kClamp);
            if (!m) {
                acc -= logf(1.0f - p) * p * p * 0.75f;   // (1-FOCAL_ALPHA)
                continue;
            }
            float l2s = log2f(scores[row]);
            float l2i = log2f(iouMap[row]);
            float logp = logf(p);
            float log1mp = logf(1.0f - p);
            float omp = 1.0f - p;
            while (m) {
                int g = __ffs(m) - 1;
                m &= m - 1;
                float t0 = conf_s[g] * l2s;
                t0 = (t0 != t0) ? 0.0f : t0;
                float raw = exp2f(t0 + l2i);    // = s^conf * iou
                float wc = (raw + kClamp) * invmx[g];
                wc = fminf(fmaxf(wc, kClamp), 1.0f - kClamp);
                float a1 = wc * omp;            // pos: -logp*(wc*(1-p))^2
                float a2 = (1.0f - wc) * p;     // boxneg: -log1mp*((1-wc)*p)^2
                acc -= (logp * a1 * a1 + log1mp * a2 * a2) * 0.25f;  // FOCAL_ALPHA
            }
        }
        for (int off = 32; off > 0; off >>= 1) acc += __shfl_down(acc, off);
        if ((tid & 63) == 0) wsum[tid >> 6] = acc;
        __syncthreads();
        if (tid == 0) lsum[bid] = wsum[0] + wsum[1] + wsum[2] + wsum[3];
    }
    __threadfence();
    grid.sync();

    // ---- Phase 4: block 0 final reduce ----
    if (bid == 0) {
        float a = 0.f;
        for (int i = tid; i < nb; i += blockDim.x) a += lsum[i];
        for (int off = 32; off > 0; off >>= 1) a += __shfl_down(a, off);
        if ((tid & 63) == 0) wsum[tid >> 6] = a;
        __syncthreads();
        if (tid == 0) {
            int iv = *(const int*)denom_ptr;    // num_pos_avg: int or float bits
            float fv = *(const float*)denom_ptr;
            float denom = (iv > 0 && iv < (1 << 24)) ? (float)iv : fv;
            out[0] = (wsum[0] + wsum[1] + wsum[2] + wsum[3]) / denom;
        }
    }
}

// ---------------------------- legacy fallback (r7) ----------------------------
__global__ void init_kernel(uint32_t* confbits, uint32_t* mxkeys, float* out) {
    int t = threadIdx.x;
    if (t < 32) { confbits[t] = 0u; mxkeys[t] = kNegInfKey; }
    if (t == 0) out[0] = 0.0f;
}

template <bool WRITE_BITS>
__global__ void pack_conf_kernel(const int4* __restrict__ boxes4,
                                 const float* __restrict__ scores,
                                 uint32_t* __restrict__ bits,
                                 uint32_t* __restrict__ confbits,
                                 long long nchunks) {
    __shared__ uint32_t conf_lds[32];
    int tid = threadIdx.x;
    if (tid < 32) conf_lds[tid] = 0u;
    __syncthreads();
    int g0 = (tid & 7) * 4;
    float r0 = 0.0f, r1 = 0.0f, r2 = 0.0f, r3 = 0.0f;
    long long stride = (long long)gridDim.x * blockDim.x;
    for (long long c = (long long)blockIdx.x * blockDim.x + tid; c < nchunks; c += stride) {
        int4 v = boxes4[c];
        uint32_t nib = (uint32_t)(v.x > 0) | ((uint32_t)(v.y > 0) << 1) |
                       ((uint32_t)(v.z > 0) << 2) | ((uint32_t)(v.w > 0) << 3);
        long long row = c >> 3;
        if (WRITE_BITS) {
            uint32_t r = nib << ((tid & 7) * 4);
            r |= __shfl_xor(r, 1);
            r |= __shfl_xor(r, 2);
            r |= __shfl_xor(r, 4);
            if ((tid & 7) == 0) bits[row] = r;
        }
        float s = scores[row];
        r0 = (nib & 1u) ? fmaxf(r0, s) : r0;
        r1 = (nib & 2u) ? fmaxf(r1, s) : r1;
        r2 = (nib & 4u) ? fmaxf(r2, s) : r2;
        r3 = (nib & 8u) ? fmaxf(r3, s) : r3;
    }
    for (int off = 8; off < 64; off <<= 1) {
        r0 = fmaxf(r0, __shfl_xor(r0, off));
        r1 = fmaxf(r1, __shfl_xor(r1, off));
        r2 = fmaxf(r2, __shfl_xor(r2, off));
        r3 = fmaxf(r3, __shfl_xor(r3, off));
    }
    if ((tid & 63) < 8) {
        atomicMax(&conf_lds[g0 + 0], __float_as_uint(r0));
        atomicMax(&conf_lds[g0 + 1], __float_as_uint(r1));
        atomicMax(&conf_lds[g0 + 2], __float_as_uint(r2));
        atomicMax(&conf_lds[g0 + 3], __float_as_uint(r3));
    }
    __syncthreads();
    if (tid < 32 && conf_lds[tid]) atomicMax(&confbits[tid], conf_lds[tid]);
}

__device__ inline uint32_t row_mask_from_boxes(const int4* __restrict__ boxes4, int row) {
    uint32_t m = 0;
#pragma unroll
    for (int k = 0; k < 8; ++k) {
        int4 v = boxes4[(long long)row * 8 + k];
        uint32_t nib = (uint32_t)(v.x > 0) | ((uint32_t)(v.y > 0) << 1) |
                       ((uint32_t)(v.z > 0) << 2) | ((uint32_t)(v.w > 0) << 3);
        m |= nib << (k * 4);
    }
    return m;
}

template <bool USE_BITS>
__global__ void mx_kernel(const uint32_t* __restrict__ bits,
                          const int4* __restrict__ boxes4,
                          const float* __restrict__ scores,
                          const float* __restrict__ iouMap,
                          const uint32_t* __restrict__ confbits,
                          uint32_t* __restrict__ mxkeys, int n) {
    __shared__ float conf_s[32];
    __shared__ float smax_w[4][32];
    int tid = threadIdx.x;
    if (tid < 32) conf_s[tid] = __uint_as_float(confbits[tid]);
    __syncthreads();
    int chunk = tid & 3;
    float cf[8], lmax[8];
#pragma unroll
    for (int k = 0; k < 8; ++k) { cf[k] = conf_s[chunk * 8 + k]; lmax[k] = -__builtin_inff(); }
    int slots = (gridDim.x * blockDim.x) >> 2;
    for (int row = (blockIdx.x * blockDim.x + tid) >> 2; row < n; row += slots) {
        uint32_t m = USE_BITS ? bits[row] : row_mask_from_boxes(boxes4, row);
        uint32_t mc = (m >> (chunk * 8)) & 0xFFu;
        if (!mc) continue;
        float l2s = log2f(scores[row]);
        float l2i = log2f(iouMap[row]);
#pragma unroll
        for (int k = 0; k < 8; ++k) {
            float t0 = cf[k] * l2s;
            t0 = (t0 != t0) ? 0.0f : t0;
            float t = t0 + l2i;
            lmax[k] = (mc & (1u << k)) ? fmaxf(lmax[k], t) : lmax[k];
        }
    }
#pragma unroll
    for (int off = 4; off < 64; off <<= 1) {
#pragma unroll
        for (int k = 0; k < 8; ++k) lmax[k] = fmaxf(lmax[k], __shfl_xor(lmax[k], off));
    }
    int wave = tid >> 6, lane = tid & 63;
    if (lane < 4) {
#pragma unroll
        for (int k = 0; k < 8; ++k) smax_w[wave][lane * 8 + k] = lmax[k];
    }
    __syncthreads();
    if (tid < 32) {
        float v = fmaxf(fmaxf(smax_w[0][tid], smax_w[1][tid]),
                        fmaxf(smax_w[2][tid], smax_w[3][tid]));
        uint32_t k = fkey(v);
        if (k != kNegInfKey) atomicMax(&mxkeys[tid], k);
    }
}

template <bool USE_BITS>
__global__ void loss_kernel(const uint32_t* __restrict__ bits,
                            const int4* __restrict__ boxes4,
                            const float* __restrict__ logits,
                            const float* __restrict__ scores,
                            const float* __restrict__ iouMap,
                            const uint32_t* __restrict__ confbits,
                            const uint32_t* __restrict__ mxkeys,
                            const void* __restrict__ denom_ptr,
                            float* __restrict__ out, int n) {
    __shared__ float conf_s[32];
    __shared__ float invmx[32];
    __shared__ float wsum[4];
    int tid = threadIdx.x;
    if (tid < 32) {
        conf_s[tid] = __uint_as_float(confbits[tid]);
        float mx = exp2f(funkey(mxkeys[tid]));
        invmx[tid] = 1.0f / (mx + kClamp);
    }
    __syncthreads();
    float acc = 0.0f;
    int stride = gridDim.x * blockDim.x;
    for (int row = blockIdx.x * blockDim.x + tid; row < n; row += stride) {
        uint32_t m = USE_BITS ? bits[row] : row_mask_from_boxes(boxes4, row);
        float x = logits[row];
        float p = 1.0f / (1.0f + expf(-x));
        p = fminf(fmaxf(p, kClamp), 1.0f - kClamp);
        if (!m) {
            acc -= logf(1.0f - p) * p * p * 0.75f;
            continue;
        }
        float l2s = log2f(scores[row]);
        float l2i = log2f(iouMap[row]);
        float logp = logf(p);
        float log1mp = logf(1.0f - p);
        float omp = 1.0f - p;
        while (m) {
            int g = __ffs(m) - 1;
            m &= m - 1;
            float t0 = conf_s[g] * l2s;
            t0 = (t0 != t0) ? 0.0f : t0;
            float raw = exp2f(t0 + l2i);
            float wc = (raw + kClamp) * invmx[g];
            wc = fminf(fmaxf(wc, kClamp), 1.0f - kClamp);
            float a1 = wc * omp;
            float a2 = (1.0f - wc) * p;
            acc -= (logp * a1 * a1 + log1mp * a2 * a2) * 0.25f;
        }
    }
    for (int off = 32; off > 0; off >>= 1) acc += __shfl_down(acc, off);
    if ((tid & 63) == 0) wsum[tid >> 6] = acc;
    __syncthreads();
    if (tid == 0) {
        int iv = *(const int*)denom_ptr;
        float fv = *(const float*)denom_ptr;
        float denom = (iv > 0 && iv < (1 << 24)) ? (float)iv : fv;
        float tot = (wsum[0] + wsum[1] + wsum[2] + wsum[3]) / denom;
        atomicAdd(out, tot);
    }
}

extern "C" void kernel_launch(void* const* d_in, const int* in_sizes, int n_in,
                              void* d_out, int out_size, void* d_ws, size_t ws_size,
                              hipStream_t stream) {
    const float* logits = (const float*)d_in[0];
    const float* scores = (const float*)d_in[1];
    const float* iou    = (const float*)d_in[2];
    const int4*  boxes4 = (const int4*)d_in[3];
    const void*  npa    = d_in[4];
    float* out = (float*)d_out;

    int n = in_sizes[0];                        // 1e6 rows
    long long nchunks = (long long)in_sizes[3] / 4;   // int4 chunks (n*32/4)

    const int nb = 1024, nt = 256;
    // fused ws layout: conf_part | mx_part | lsum | bits
    float* conf_part = (float*)d_ws;            // nb*32 floats (128 KB)
    float* mx_part   = conf_part + nb * 32;     // nb*32 floats (128 KB)
    float* lsum      = mx_part + nb * 32;       // nb floats (4 KB)
    uint32_t* bits_f = (uint32_t*)(lsum + nb);  // n uint32 (4 MB)
    size_t need = sizeof(float) * (size_t)(nb * 64 + nb) + sizeof(uint32_t) * (size_t)n;

    if (ws_size >= need) {
        void* args[] = { (void*)&logits, (void*)&scores, (void*)&iou, (void*)&boxes4,
                         (void*)&npa, (void*)&out, (void*)&conf_part, (void*)&mx_part,
                         (void*)&lsum, (void*)&bits_f, (void*)&n, (void*)&nchunks };
        hipError_t e = hipLaunchCooperativeKernel((const void*)fused_kernel,
                                                  dim3(nb), dim3(nt), args, 0, stream);
        if (e == hipSuccess) return;
        (void)hipGetLastError();                // clear error, fall through to legacy
    }

    // legacy 4-kernel path (r7, known-passing)
    uint32_t* confbits = (uint32_t*)d_ws;
    uint32_t* mxkeys   = confbits + 32;
    uint32_t* bits     = confbits + 64;
    bool use_bits = ws_size >= (size_t)n * 4 + 256;

    init_kernel<<<1, 64, 0, stream>>>(confbits, mxkeys, out);
    if (use_bits) {
        pack_conf_kernel<true><<<2048, 256, 0, stream>>>(boxes4, scores, bits, confbits, nchunks);
        mx_kernel<true><<<512, 256, 0, stream>>>(bits, nullptr, scores, iou, confbits, mxkeys, n);
        loss_kernel<true><<<1024, 256, 0, stream>>>(bits, nullptr, logits, scores, iou,
                                                    confbits, mxkeys, npa, out, n);
    } else {
        pack_conf_kernel<false><<<2048, 256, 0, stream>>>(boxes4, scores, nullptr, confbits, nchunks);
        mx_kernel<false><<<512, 256, 0, stream>>>(nullptr, boxes4, scores, iou, confbits, mxkeys, n);
        loss_kernel<false><<<1024, 256, 0, stream>>>(nullptr, boxes4, logits, scores, iou,
                                                     confbits, mxkeys, npa, out, n);
    }
}

// Round 9
// 279.305 us; speedup vs baseline: 2.7619x; 2.7619x over previous
//
#include <hip/hip_runtime.h>
#include <hip/hip_bf16.h>
#include <stdint.h>

// BOXLoss: N=1e6 rows, G=32 groups -> scalar loss. 3 dispatches, no init kernel.
// K1 pack: bits (1 bit/entry) + per-block conf partials (plain writes, no init);
//          block0 inits mxkeys/out for later kernels (stream-ordered).
// K2 mx:   redundant per-block conf_part reduce -> conf_s; log-space lmax[8]
//          register partials (r6 lesson: lmax[32] spilled); one-time atomicMax.
// K3 loss: focal loss; invmx precomputed; one atomicAdd per block.
// r8 lesson: grid.sync+threadfence fusion = 630us (cross-XCD coherence) — never again.

constexpr float kClamp = 1e-4f;
constexpr uint32_t kNegInfKey = 0x007FFFFFu;  // fkey(-inf)

__device__ inline uint32_t fkey(float f) {    // monotone float -> uint
    uint32_t u = __float_as_uint(f);
    return (u & 0x80000000u) ? ~u : (u | 0x80000000u);
}
__device__ inline float funkey(uint32_t k) {
    uint32_t u = (k & 0x80000000u) ? (k ^ 0x80000000u) : ~k;
    return __uint_as_float(u);
}

// ws layout (floats): [0..31] mxkeys(u32) | [32..63] conf_final | [64..64+NB*32) conf_part | bits
constexpr int kNB = 2048;                      // pack grid; conf_part is kNB*32

// ---- K1: 8 lanes = 1 row (G=32); each lane handles one int4 (4 entries) ----
__global__ __launch_bounds__(256)
void pack_kernel(const int4* __restrict__ boxes4,
                 const float* __restrict__ scores,
                 uint32_t* __restrict__ bits,
                 float* __restrict__ conf_part,
                 uint32_t* __restrict__ mxkeys,
                 float* __restrict__ out,
                 long long nchunks) {
    __shared__ uint32_t conf_lds[32];
    int tid = threadIdx.x;
    if (tid < 32) conf_lds[tid] = 0u;
    if (blockIdx.x == 0) {                     // init for LATER kernels (stream-ordered)
        if (tid < 32) mxkeys[tid] = kNegInfKey;
        if (tid == 0) out[0] = 0.0f;
    }
    __syncthreads();
    const int g0 = (tid & 7) * 4;
    float r0 = 0.f, r1 = 0.f, r2 = 0.f, r3 = 0.f;   // per-lane column maxima
    const long long stride = (long long)gridDim.x * blockDim.x;
    for (long long c = (long long)blockIdx.x * blockDim.x + tid; c < nchunks; c += stride) {
        int4 v = boxes4[c];
        uint32_t nib = (uint32_t)(v.x > 0) | ((uint32_t)(v.y > 0) << 1) |
                       ((uint32_t)(v.z > 0) << 2) | ((uint32_t)(v.w > 0) << 3);
        long long row = c >> 3;
        uint32_t r = nib << ((tid & 7) * 4);
        r |= __shfl_xor(r, 1);
        r |= __shfl_xor(r, 2);
        r |= __shfl_xor(r, 4);                  // 8-lane OR -> full row mask
        if ((tid & 7) == 0) bits[row] = r;
        float s = scores[row];                  // broadcast within 8 lanes, cached
        r0 = (nib & 1u) ? fmaxf(r0, s) : r0;
        r1 = (nib & 2u) ? fmaxf(r1, s) : r1;
        r2 = (nib & 4u) ? fmaxf(r2, s) : r2;
        r3 = (nib & 8u) ? fmaxf(r3, s) : r3;
    }
    for (int off = 8; off < 64; off <<= 1) {    // lanes sharing the column set
        r0 = fmaxf(r0, __shfl_xor(r0, off));
        r1 = fmaxf(r1, __shfl_xor(r1, off));
        r2 = fmaxf(r2, __shfl_xor(r2, off));
        r3 = fmaxf(r3, __shfl_xor(r3, off));
    }
    if ((tid & 63) < 8) {                       // one-time LDS merge (scores >= 0)
        atomicMax(&conf_lds[g0 + 0], __float_as_uint(r0));
        atomicMax(&conf_lds[g0 + 1], __float_as_uint(r1));
        atomicMax(&conf_lds[g0 + 2], __float_as_uint(r2));
        atomicMax(&conf_lds[g0 + 3], __float_as_uint(r3));
    }
    __syncthreads();
    if (tid < 32) conf_part[blockIdx.x * 32 + tid] = __uint_as_float(conf_lds[tid]);
}

// ---- K2: conf reduce (redundant/block) + mx partials (4 threads/row, 8 cols) ----
__global__ __launch_bounds__(256)
void mx_kernel(const uint32_t* __restrict__ bits,
               const float* __restrict__ scores,
               const float* __restrict__ iouMap,
               const float* __restrict__ conf_part,
               float* __restrict__ conf_final,
               uint32_t* __restrict__ mxkeys, int n) {
    __shared__ float red[32][33];
    __shared__ float conf_s[32];
    __shared__ float smax_w[4][32];
    const int tid = threadIdx.x;
    {   // reduce conf_part[kNB*32] -> conf_s (each block redundantly)
        const float4* cp4 = (const float4*)conf_part;
        float4 m = make_float4(0.f, 0.f, 0.f, 0.f);
        const int slot = tid & 7, slice = tid >> 3;
        for (int b = slice; b < kNB; b += 32) { // 64 float4 iters/thread, L2-resident
            float4 v = cp4[b * 8 + slot];
            m.x = fmaxf(m.x, v.x); m.y = fmaxf(m.y, v.y);
            m.z = fmaxf(m.z, v.z); m.w = fmaxf(m.w, v.w);
        }
        red[slice][slot * 4 + 0] = m.x; red[slice][slot * 4 + 1] = m.y;
        red[slice][slot * 4 + 2] = m.z; red[slice][slot * 4 + 3] = m.w;
        __syncthreads();
        if (tid < 32) {
            float v = red[0][tid];
            for (int s = 1; s < 32; ++s) v = fmaxf(v, red[s][tid]);
            conf_s[tid] = v;
            conf_final[tid] = v;                // all blocks write identical values
        }
        __syncthreads();
    }
    const int chunk = tid & 3;
    float cf[8], lmax[8];
#pragma unroll
    for (int k = 0; k < 8; ++k) { cf[k] = conf_s[chunk * 8 + k]; lmax[k] = -__builtin_inff(); }
    const int slots = (gridDim.x * blockDim.x) >> 2;
    for (int row = (blockIdx.x * blockDim.x + tid) >> 2; row < n; row += slots) {
        uint32_t mc = (bits[row] >> (chunk * 8)) & 0xFFu;
        if (!mc) continue;
        float l2s = log2f(scores[row]);         // -inf for s==0
        float l2i = log2f(iouMap[row]);
#pragma unroll
        for (int k = 0; k < 8; ++k) {
            float t0 = cf[k] * l2s;
            t0 = (t0 != t0) ? 0.0f : t0;        // 0*-inf (pow(0,0)=1) -> 0
            float t = t0 + l2i;
            lmax[k] = (mc & (1u << k)) ? fmaxf(lmax[k], t) : lmax[k];
        }
    }
#pragma unroll
    for (int off = 4; off < 64; off <<= 1) {    // butterfly over lanes sharing a chunk
#pragma unroll
        for (int k = 0; k < 8; ++k) lmax[k] = fmaxf(lmax[k], __shfl_xor(lmax[k], off));
    }
    const int wave = tid >> 6, lane = tid & 63;
    if (lane < 4) {
#pragma unroll
        for (int k = 0; k < 8; ++k) smax_w[wave][lane * 8 + k] = lmax[k];
    }
    __syncthreads();
    if (tid < 32) {
        float v = fmaxf(fmaxf(smax_w[0][tid], smax_w[1][tid]),
                        fmaxf(smax_w[2][tid], smax_w[3][tid]));
        uint32_t k = fkey(v);
        if (k != kNegInfKey) atomicMax(&mxkeys[tid], k);  // one-time, 32/block
    }
}

// ---- K3: focal loss ----
__global__ __launch_bounds__(256)
void loss_kernel(const uint32_t* __restrict__ bits,
                 const float* __restrict__ logits,
                 const float* __restrict__ scores,
                 const float* __restrict__ iouMap,
                 const float* __restrict__ conf_final,
                 const uint32_t* __restrict__ mxkeys,
                 const void* __restrict__ denom_ptr,
                 float* __restrict__ out, int n) {
    __shared__ float conf_s[32];
    __shared__ float invmx[32];
    __shared__ float wsum[4];
    const int tid = threadIdx.x;
    if (tid < 32) {
        conf_s[tid] = conf_final[tid];
        float mx = exp2f(funkey(mxkeys[tid])); // -inf key -> mx=0 (unused cols)
        invmx[tid] = 1.0f / (mx + kClamp);
    }
    __syncthreads();
    float acc = 0.0f;
    const int stride = gridDim.x * blockDim.x;
    for (int row = blockIdx.x * blockDim.x + tid; row < n; row += stride) {
        uint32_t m = bits[row];
        float x = logits[row];
        float p = 1.0f / (1.0f + expf(-x));
        p = fminf(fmaxf(p, kClamp), 1.0f - kClamp);
        if (!m) {
            acc -= logf(1.0f - p) * p * p * 0.75f;   // (1-FOCAL_ALPHA)
            continue;
        }
        float l2s = log2f(scores[row]);
        float l2i = log2f(iouMap[row]);
        float logp = logf(p);
        float log1mp = logf(1.0f - p);
        float omp = 1.0f - p;
        while (m) {
            int g = __ffs(m) - 1;
            m &= m - 1;
            float t0 = conf_s[g] * l2s;
            t0 = (t0 != t0) ? 0.0f : t0;
            float raw = exp2f(t0 + l2i);        // = s^conf * iou
            float wc = (raw + kClamp) * invmx[g];
            wc = fminf(fmaxf(wc, kClamp), 1.0f - kClamp);
            float a1 = wc * omp;                // pos: -logp*(wc*(1-p))^2
            float a2 = (1.0f - wc) * p;         // boxneg: -log1mp*((1-wc)*p)^2
            acc -= (logp * a1 * a1 + log1mp * a2 * a2) * 0.25f;  // FOCAL_ALPHA
        }
    }
    for (int off = 32; off > 0; off >>= 1) acc += __shfl_down(acc, off);
    if ((tid & 63) == 0) wsum[tid >> 6] = acc;
    __syncthreads();
    if (tid == 0) {
        int iv = *(const int*)denom_ptr;        // num_pos_avg: int or float bits
        float fv = *(const float*)denom_ptr;
        float denom = (iv > 0 && iv < (1 << 24)) ? (float)iv : fv;
        atomicAdd(out, (wsum[0] + wsum[1] + wsum[2] + wsum[3]) / denom);
    }
}

extern "C" void kernel_launch(void* const* d_in, const int* in_sizes, int n_in,
                              void* d_out, int out_size, void* d_ws, size_t ws_size,
                              hipStream_t stream) {
    const float* logits = (const float*)d_in[0];
    const float* scores = (const float*)d_in[1];
    const float* iou    = (const float*)d_in[2];
    const int4*  boxes4 = (const int4*)d_in[3];
    const void*  npa    = d_in[4];
    float* out = (float*)d_out;

    int n = in_sizes[0];                        // 1e6 rows
    long long nchunks = (long long)in_sizes[3] / 4;   // n*32/4 int4 chunks

    uint32_t* mxkeys     = (uint32_t*)d_ws;     // [0..31]
    float*    conf_final = (float*)d_ws + 32;   // [32..63]
    float*    conf_part  = (float*)d_ws + 64;   // kNB*32 floats (256 KB)
    uint32_t* bits       = (uint32_t*)((float*)d_ws + 64 + kNB * 32);  // n u32 (4 MB)

    pack_kernel<<<kNB, 256, 0, stream>>>(boxes4, scores, bits, conf_part, mxkeys, out, nchunks);
    mx_kernel<<<512, 256, 0, stream>>>(bits, scores, iou, conf_part, conf_final, mxkeys, n);
    loss_kernel<<<1024, 256, 0, stream>>>(bits, logits, scores, iou, conf_final, mxkeys,
                                          npa, out, n);
}